// Round 5
// baseline (291.217 us; speedup 1.0000x reference)
//
#include <hip/hip_runtime.h>

// B=16, T=2048, C=1024, H=64. out = causal-softmax(QK^T/8) V
// x fp32 [B,T,C]; Wq/Wk/Wv fp32 [C,H]; out fp32 [B,T,H].

#define B_ 16
#define T_ 2048
#define C_ 1024
#define H_ 64
#define QK_ELEMS (B_ * T_ * H_)

typedef float  f32x4  __attribute__((ext_vector_type(4)));
typedef __bf16 bf16x8 __attribute__((ext_vector_type(8)));
typedef __bf16 bf16x4 __attribute__((ext_vector_type(4)));

__device__ __forceinline__ void glds16(const void* g, void* l) {
    __builtin_amdgcn_global_load_lds(
        (const __attribute__((address_space(1))) void*)g,
        (__attribute__((address_space(3))) void*)l, 16, 0, 0);
}

// ---------------------------------------------------------------------------
// Kernel 0: W [C,H] fp32 (x3) -> Wt [192][1024] bf16 transposed, LINEAR
// (B-fragments now go straight to registers — no LDS, no swizzle needed).
// ---------------------------------------------------------------------------
__global__ __launch_bounds__(256) void wt_kernel(const float* __restrict__ Wq,
                                                 const float* __restrict__ Wk,
                                                 const float* __restrict__ Wv,
                                                 __bf16* __restrict__ Wt) {
    __shared__ float tl[64][65];
    const int mat = blockIdx.x >> 4;
    const int c0  = (blockIdx.x & 15) * 64;
    const float* W = (mat == 0) ? Wq : (mat == 1) ? Wk : Wv;
    const int t  = threadIdx.x;
    const int r4 = t >> 6;
    const int cc = t & 63;
#pragma unroll
    for (int i = 0; i < 16; i++) {
        const int c = r4 + i * 4;
        tl[c][cc] = W[(size_t)(c0 + c) * H_ + cc];
    }
    __syncthreads();
#pragma unroll
    for (int i = 0; i < 16; i++) {
        const int h = r4 + i * 4;
        Wt[(size_t)mat * 65536 + (size_t)h * C_ + c0 + cc] = (__bf16)tl[cc][h];
    }
}

// ---------------------------------------------------------------------------
// Kernel 1: QKV projection — BARRIER-FREE K-loop, no LDS staging.
// Block 256 thr (4 waves), M=64 x N=192. Wave w owns cols w*48..+47 (3 nt),
// all 64 rows (4 mt) -> 12 acc tiles. Half-step = BK=32 (32 steps).
// A: fp32 register sets, 3-way rotation, prefetch distance 2 (fully
//    unrolled loop -> all indices compile-time; cvt to bf16 at USE so the
//    vmcnt wait lands at the consumer, not the prefetch site).
// B: bf16 register sets from L2-resident Wt (read once per block).
// Grid 512 = 2 waves/SIMD -> VGPR budget 256; this uses ~200.
// Epilogue: Q linear, K chunk-swizzled, V transposed+swizzled via tiny LDS.
// ---------------------------------------------------------------------------
__global__ __launch_bounds__(256, 2) void qkv_kernel(const float* __restrict__ x,
                                                     const __bf16* __restrict__ Wt,
                                                     __bf16* __restrict__ Qw,
                                                     __bf16* __restrict__ Kw,
                                                     __bf16* __restrict__ Vtw) {
    __shared__ __align__(16) __bf16 Vt_l[64 * 72];

    const int tid  = threadIdx.x;
    const int w    = tid >> 6;
    const int lane = tid & 63;
    const int quad = lane >> 4;
    const int l15  = lane & 15;
    const int m0   = blockIdx.x * 64;

    f32x4 acc[12];                         // [mt*3 + nt]
#pragma unroll
    for (int i = 0; i < 12; i++) acc[i] = (f32x4){0.f, 0.f, 0.f, 0.f};

    // lane base pointers: A rows m0+mt*16+l15, cols h*32+quad*8;
    //                     B rows w*48+nt*16+l15, cols h*32+quad*8
    const float*  xb = x  + (size_t)(m0 + l15) * C_ + quad * 8;
    const __bf16* wb = Wt + (size_t)(w * 48 + l15) * C_ + quad * 8;

    float4 Aset[3][8];                     // [set][mt*2 + half] fp32
    bf16x8 Bset[3][3];                     // [set][nt]

    auto loadSet = [&](int h, int s) {
#pragma unroll
        for (int mt = 0; mt < 4; mt++) {
            const float* p = xb + (size_t)mt * 16 * C_ + h * 32;
            Aset[s][mt * 2]     = *(const float4*)p;
            Aset[s][mt * 2 + 1] = *(const float4*)(p + 4);
        }
#pragma unroll
        for (int nt = 0; nt < 3; nt++)
            Bset[s][nt] = *(const bf16x8*)(wb + (size_t)nt * 16 * C_ + h * 32);
    };

    loadSet(0, 0);
    loadSet(1, 1);

#pragma unroll
    for (int h = 0; h < 32; h++) {
        if (h + 2 < 32) loadSet(h + 2, (h + 2) % 3);
        const int s = h % 3;
        bf16x8 af[4];
#pragma unroll
        for (int mt = 0; mt < 4; mt++) {
            const float4 f0 = Aset[s][mt * 2];
            const float4 f1 = Aset[s][mt * 2 + 1];
            af[mt][0] = (__bf16)f0.x; af[mt][1] = (__bf16)f0.y;
            af[mt][2] = (__bf16)f0.z; af[mt][3] = (__bf16)f0.w;
            af[mt][4] = (__bf16)f1.x; af[mt][5] = (__bf16)f1.y;
            af[mt][6] = (__bf16)f1.z; af[mt][7] = (__bf16)f1.w;
        }
#pragma unroll
        for (int mt = 0; mt < 4; mt++)
#pragma unroll
            for (int nt = 0; nt < 3; nt++)
                acc[mt * 3 + nt] = __builtin_amdgcn_mfma_f32_16x16x32_bf16(
                    af[mt], Bset[s][nt], acc[mt * 3 + nt], 0, 0, 0);
    }

    // ---- epilogue: cols 0..63 Q (linear), 64..127 K (swizzled),
    //      128..191 V (transpose via LDS, then swizzled writeout)
#pragma unroll
    for (int mt = 0; mt < 4; mt++) {
        const int row0 = m0 + mt * 16 + quad * 4;
#pragma unroll
        for (int nt = 0; nt < 3; nt++) {
            const int col = w * 48 + nt * 16 + l15;
            const f32x4 a = acc[mt * 3 + nt];
            if (col < 64) {
#pragma unroll
                for (int r = 0; r < 4; r++)
                    Qw[(size_t)(row0 + r) * H_ + col] = (__bf16)a[r];
            } else if (col < 128) {
                const int h = col - 64;
#pragma unroll
                for (int r = 0; r < 4; r++) {
                    const int row = row0 + r;
                    const int hs  = (((h >> 3) ^ (row & 7)) << 3) | (h & 7);
                    Kw[(size_t)row * H_ + hs] = (__bf16)a[r];
                }
            } else {
                const int h  = col - 128;
                const int t0 = mt * 16 + quad * 4;
                bf16x4 pv;
                pv[0] = (__bf16)a[0]; pv[1] = (__bf16)a[1];
                pv[2] = (__bf16)a[2]; pv[3] = (__bf16)a[3];
                *(bf16x4*)&Vt_l[h * 72 + t0] = pv;
            }
        }
    }
    __syncthreads();
    {
        const int bb   = m0 >> 11;
        const int tblk = m0 & 2047;
#pragma unroll
        for (int i = 0; i < 2; i++) {
            const int idx = tid + i * 256;          // 0..511
            const int h   = idx >> 3;
            const int c   = idx & 7;                // dst t-chunk
            const int sc  = c ^ (h & 7);            // src chunk (swizzle)
            *(bf16x8*)(Vtw + (((size_t)(bb * H_ + h)) << 11) + tblk + c * 8) =
                *(const bf16x8*)&Vt_l[h * 72 + sc * 8];
        }
    }
}

// ---------------------------------------------------------------------------
// Kernel 2: paired causal flash attention (UNCHANGED from round 4 — passed).
// ---------------------------------------------------------------------------
#define SCALE_LOG2E 0.18033688011112042f   // (1/sqrt(64)) * log2(e)

__global__ __launch_bounds__(256) void attn_kernel(const __bf16* __restrict__ Qw,
                                                   const __bf16* __restrict__ Kw,
                                                   const __bf16* __restrict__ Vtw,
                                                   float* __restrict__ Opart,
                                                   float* __restrict__ Lpart) {
    __shared__ __align__(16) __bf16 Klds[2][64 * 64];
    __shared__ __align__(16) __bf16 Vlds[2][64 * 64];
    __shared__ __align__(16) __bf16 Plds[2][4][16 * 72];

    const int tid  = threadIdx.x;
    const int w    = tid >> 6;
    const int lane = tid & 63;
    const int quad = lane >> 4;
    const int l15  = lane & 15;

    const int b   = blockIdx.x & 15;
    const int cid = blockIdx.x >> 4;          // 0..39, heavy chunks first
    int i, ci;
    if (cid < 16)      { i = 15 - (cid >> 2); ci = cid & 3; }
    else if (cid < 28) { const int u = cid - 16; i = 11 - u / 3; ci = u % 3; }
    else if (cid < 36) { const int u = cid - 28; i = 7 - (u >> 1); ci = u & 1; }
    else               { i = 3 - (cid - 36); ci = 0; }

    const int jmax = 2 * i + 1;
    const int j0 = ci * 8;
    const int j1 = (j0 + 8 < jmax + 1) ? j0 + 8 : jmax + 1;
    const int nj = j1 - j0;
    const int qA0 = 2 * i * 64;
    const size_t bT = (size_t)b * T_;

    const __bf16* qpA = Qw + (bT + qA0 + w * 16 + l15) * H_ + quad * 8;
    const bf16x8 qfA0 = *(const bf16x8*)qpA;
    const bf16x8 qfA1 = *(const bf16x8*)(qpA + 32);
    const bf16x8 qfB0 = *(const bf16x8*)(qpA + 64 * H_);
    const bf16x8 qfB1 = *(const bf16x8*)(qpA + 64 * H_ + 32);

    float lA = 0.f, lB = 0.f;
    f32x4 accA[4], accB[4];
#pragma unroll
    for (int nt = 0; nt < 4; nt++) {
        accA[nt] = (f32x4){0.f, 0.f, 0.f, 0.f};
        accB[nt] = (f32x4){0.f, 0.f, 0.f, 0.f};
    }

    auto stage = [&](int ts0, int buf) {
        const __bf16* Ks = Kw + (bT + ts0) * H_;
        const __bf16* Vs = Vtw + (((size_t)(b * H_)) << 11) + ts0;
#pragma unroll
        for (int c = 0; c < 2; c++) {
            const int g   = w * 2 + c;
            const int row = g * 8 + (lane >> 3);
            const int cb  = (lane & 7) * 8;
            glds16(Ks + (size_t)row * H_ + cb, &Klds[buf][g * 512]);
            glds16(Vs + ((size_t)row << 11) + cb, &Vlds[buf][g * 512]);
        }
    };

    stage(j0 * 64, 0);

    for (int jj = 0; jj < nj; jj++) {
        const int j = j0 + jj;
        __syncthreads();
        if (jj + 1 < nj) stage((j + 1) * 64, (jj + 1) & 1);
        const int buf = jj & 1;
        const bool doA = (j <= 2 * i);
        const int ts0 = j * 64;
        const int qgA = qA0 + w * 16 + l15;

#pragma unroll
        for (int nt = 0; nt < 4; nt++) {
            const __bf16* kb = &Klds[buf][(nt * 16 + l15) * 64];
            bf16x8 kf0 = *(const bf16x8*)(kb + ((quad ^ (l15 & 7)) << 3));
            bf16x8 kf1 = *(const bf16x8*)(kb + (((4 + quad) ^ (l15 & 7)) << 3));
            const int key0 = ts0 + nt * 16 + quad * 4;

            if (doA) {
                f32x4 z = (f32x4){0.f, 0.f, 0.f, 0.f};
                z = __builtin_amdgcn_mfma_f32_16x16x32_bf16(kf0, qfA0, z, 0, 0, 0);
                z = __builtin_amdgcn_mfma_f32_16x16x32_bf16(kf1, qfA1, z, 0, 0, 0);
                bf16x4 pv;
#pragma unroll
                for (int r = 0; r < 4; r++) {
                    float e = exp2f(__builtin_fmaf(z[r], SCALE_LOG2E, -8.0f));
                    if (j == 2 * i && key0 + r > qgA) e = 0.f;
                    pv[r] = (__bf16)e;
                    lA += e;
                }
                *(bf16x4*)&Plds[0][w][l15 * 72 + nt * 16 + quad * 4] = pv;
            }
            {
                f32x4 z = (f32x4){0.f, 0.f, 0.f, 0.f};
                z = __builtin_amdgcn_mfma_f32_16x16x32_bf16(kf0, qfB0, z, 0, 0, 0);
                z = __builtin_amdgcn_mfma_f32_16x16x32_bf16(kf1, qfB1, z, 0, 0, 0);
                bf16x4 pv;
#pragma unroll
                for (int r = 0; r < 4; r++) {
                    float e = exp2f(__builtin_fmaf(z[r], SCALE_LOG2E, -8.0f));
                    if (j == jmax && key0 + r > qgA + 64) e = 0.f;
                    pv[r] = (__bf16)e;
                    lB += e;
                }
                *(bf16x4*)&Plds[1][w][l15 * 72 + nt * 16 + quad * 4] = pv;
            }
        }
        __asm__ __volatile__("s_waitcnt lgkmcnt(0)" ::: "memory");

        const __bf16* prA = &Plds[0][w][l15 * 72];
        const __bf16* prB = &Plds[1][w][l15 * 72];
        bf16x8 pfA0, pfA1;
        if (doA) {
            pfA0 = *(const bf16x8*)(prA + quad * 8);
            pfA1 = *(const bf16x8*)(prA + 32 + quad * 8);
        }
        bf16x8 pfB0 = *(const bf16x8*)(prB + quad * 8);
        bf16x8 pfB1 = *(const bf16x8*)(prB + 32 + quad * 8);
#pragma unroll
        for (int nt = 0; nt < 4; nt++) {
            const __bf16* vb = &Vlds[buf][(nt * 16 + l15) * 64];
            bf16x8 vf0 = *(const bf16x8*)(vb + ((quad ^ (l15 & 7)) << 3));
            bf16x8 vf1 = *(const bf16x8*)(vb + (((4 + quad) ^ (l15 & 7)) << 3));
            if (doA) {
                accA[nt] = __builtin_amdgcn_mfma_f32_16x16x32_bf16(pfA0, vf0, accA[nt], 0, 0, 0);
                accA[nt] = __builtin_amdgcn_mfma_f32_16x16x32_bf16(pfA1, vf1, accA[nt], 0, 0, 0);
            }
            accB[nt] = __builtin_amdgcn_mfma_f32_16x16x32_bf16(pfB0, vf0, accB[nt], 0, 0, 0);
            accB[nt] = __builtin_amdgcn_mfma_f32_16x16x32_bf16(pfB1, vf1, accB[nt], 0, 0, 0);
        }
    }

    lA += __shfl_xor(lA, 16); lA += __shfl_xor(lA, 32);
    lB += __shfl_xor(lB, 16); lB += __shfl_xor(lB, 32);

    const int qiA = 2 * i;
    const int slotA = ((((b << 5) + qiA) << 2) + ci);
    const int slotB = ((((b << 5) + qiA + 1) << 2) + ci);
    float* OpA = Opart + (size_t)slotA * 4096;
    float* OpB = Opart + (size_t)slotB * 4096;
#pragma unroll
    for (int nt = 0; nt < 4; nt++)
#pragma unroll
        for (int r = 0; r < 4; r++) {
            const int o = (w * 16 + quad * 4 + r) * 64 + nt * 16 + l15;
            OpA[o] = accA[nt][r];
            OpB[o] = accB[nt][r];
        }
    if (quad == 0) {
        Lpart[slotA * 64 + w * 16 + l15] = lA;
        Lpart[slotB * 64 + w * 16 + l15] = lB;
    }
}

// ---------------------------------------------------------------------------
// Kernel 3: combine chunk partials (unchanged).
// ---------------------------------------------------------------------------
__global__ __launch_bounds__(256) void reduce_kernel(const float* __restrict__ Opart,
                                                     const float* __restrict__ Lpart,
                                                     float* __restrict__ out) {
    const int b  = blockIdx.x & 15;
    const int qi = blockIdx.x >> 4;
    const int nc = ((qi & ~1) + 9) >> 3;
    const int tid = threadIdx.x;
    const int q  = tid >> 2;
    const int hc = (tid & 3) * 16;
    const int sbase = ((b << 5) + qi) << 2;

    f32x4 s[4];
#pragma unroll
    for (int i = 0; i < 4; i++) s[i] = (f32x4){0.f, 0.f, 0.f, 0.f};
    float l = 0.f;
    for (int ci = 0; ci < nc; ci++) {
        const float* Op = Opart + (size_t)(sbase + ci) * 4096 + q * 64 + hc;
#pragma unroll
        for (int i = 0; i < 4; i++) s[i] += *(const f32x4*)(Op + i * 4);
        l += Lpart[(sbase + ci) * 64 + q];
    }
    const float inv = 1.f / l;
    float* o = out + ((size_t)b * T_ + qi * 64 + q) * H_ + hc;
#pragma unroll
    for (int i = 0; i < 4; i++) {
        f32x4 r = s[i] * inv;
        *(f32x4*)(o + i * 4) = r;
    }
}

// ---------------------------------------------------------------------------
extern "C" void kernel_launch(void* const* d_in, const int* in_sizes, int n_in,
                              void* d_out, int out_size, void* d_ws, size_t ws_size,
                              hipStream_t stream) {
    const float* x  = (const float*)d_in[0];
    const float* Wq = (const float*)d_in[1];
    const float* Wk = (const float*)d_in[2];
    const float* Wv = (const float*)d_in[3];
    float* out = (float*)d_out;

    __bf16* Qw  = (__bf16*)d_ws;
    __bf16* Kw  = Qw + QK_ELEMS;
    __bf16* Vtw = Kw + QK_ELEMS;
    __bf16* Wt  = Vtw + QK_ELEMS;
    float* Opart = (float*)((char*)d_ws + 16777216);
    float* Lpart = Opart + (size_t)2048 * 4096;

    wt_kernel<<<dim3(48), dim3(256), 0, stream>>>(Wq, Wk, Wv, Wt);
    qkv_kernel<<<dim3((B_ * T_) / 64), dim3(256), 0, stream>>>(x, Wt, Qw, Kw, Vtw);
    attn_kernel<<<dim3(640), dim3(256), 0, stream>>>(Qw, Kw, Vtw, Opart, Lpart);
    reduce_kernel<<<dim3(512), dim3(256), 0, stream>>>(Opart, Lpart, out);
}

// Round 6
// 267.425 us; speedup vs baseline: 1.0890x; 1.0890x over previous
//
#include <hip/hip_runtime.h>

// B=16, T=2048, C=1024, H=64. out = causal-softmax(QK^T/8) V
// x fp32 [B,T,C]; Wq/Wk/Wv fp32 [C,H]; out fp32 [B,T,H].

#define B_ 16
#define T_ 2048
#define C_ 1024
#define H_ 64
#define QK_ELEMS (B_ * T_ * H_)

typedef float  f32x4  __attribute__((ext_vector_type(4)));
typedef __bf16 bf16x8 __attribute__((ext_vector_type(8)));
typedef __bf16 bf16x4 __attribute__((ext_vector_type(4)));

__device__ __forceinline__ void glds16(const void* g, void* l) {
    __builtin_amdgcn_global_load_lds(
        (const __attribute__((address_space(1))) void*)g,
        (__attribute__((address_space(3))) void*)l, 16, 0, 0);
}

// ---------------------------------------------------------------------------
// Kernel 0: W [C,H] fp32 (x3) -> Wt [192][1024] bf16 transposed, LINEAR.
// ---------------------------------------------------------------------------
__global__ __launch_bounds__(256) void wt_kernel(const float* __restrict__ Wq,
                                                 const float* __restrict__ Wk,
                                                 const float* __restrict__ Wv,
                                                 __bf16* __restrict__ Wt) {
    __shared__ float tl[64][65];
    const int mat = blockIdx.x >> 4;
    const int c0  = (blockIdx.x & 15) * 64;
    const float* W = (mat == 0) ? Wq : (mat == 1) ? Wk : Wv;
    const int t  = threadIdx.x;
    const int r4 = t >> 6;
    const int cc = t & 63;
#pragma unroll
    for (int i = 0; i < 16; i++) {
        const int c = r4 + i * 4;
        tl[c][cc] = W[(size_t)(c0 + c) * H_ + cc];
    }
    __syncthreads();
#pragma unroll
    for (int i = 0; i < 16; i++) {
        const int h = r4 + i * 4;
        Wt[(size_t)mat * 65536 + (size_t)h * C_ + c0 + cc] = (__bf16)tl[cc][h];
    }
}

// ---------------------------------------------------------------------------
// Kernel 1: QKV projection, OCCUPANCY-FIRST. Tile M=32 x N=192, BK=32,
// grid 1024 -> 4 blocks/CU (29.7 KB LDS, <=128 VGPR). Each SIMD hosts 4
// waves from 4 DIFFERENT blocks -> independent barriers hide each other's
// vmcnt drains (the r4/r5 latency stall).
// B: global_load_lds into unpadded LDS, conflict-free via SOURCE-side XOR
//    swizzle (paired-row phys layout [96][8 chunks], pc=(c+4(r&1))^((r>>1)&7)).
// A: 1 float4/thread -> cvt -> padded LDS (stride 40).
// Wave w owns cols w*48..+47 (3 nt), rows 0..31 (2 mt) -> 6 MFMA/step.
// ---------------------------------------------------------------------------
__global__ __launch_bounds__(256, 4) void qkv_kernel(const float* __restrict__ x,
                                                     const __bf16* __restrict__ Wt,
                                                     __bf16* __restrict__ Qw,
                                                     __bf16* __restrict__ Kw,
                                                     __bf16* __restrict__ Vtw) {
    __shared__ __align__(16) __bf16 Alds[2][32 * 40];     // 5120 B (reused as VtL)
    __shared__ __align__(16) __bf16 Blds[2][192 * 32];    // 24576 B, phys [96][8ch]

    const int tid  = threadIdx.x;
    const int w    = tid >> 6;
    const int lane = tid & 63;
    const int quad = lane >> 4;
    const int l15  = lane & 15;
    const int m0   = blockIdx.x * 32;

    f32x4 acc[6];                          // [mt*3 + nt]
#pragma unroll
    for (int i = 0; i < 6; i++) acc[i] = (f32x4){0.f, 0.f, 0.f, 0.f};

    // A staging: thread -> row ar (0..31), 4-col group ac
    const int ar = tid >> 3;
    const int ac = (tid & 7) * 4;
    const float* xA = x + (size_t)(m0 + ar) * C_ + ac;

    // B staging source offsets (3 glds/thread/step), inverse of the phys swizzle
    int bsrc_off[3];
#pragma unroll
    for (int i = 0; i < 3; i++) {
        const int P  = i * 256 + w * 64 + lane;   // phys chunk index 0..767
        const int pr = P >> 3, pc = P & 7;
        const int s  = pc ^ (pr & 7);
        const int rl = pr * 2 + (s >> 2);         // logical Wt row 0..191
        const int c  = s & 3;                     // logical k-chunk 0..3
        bsrc_off[i] = rl * C_ + c * 8;
    }

    float4 a_reg;
    auto loadA = [&](int k0) { a_reg = *(const float4*)(xA + k0); };
    auto storeA = [&](int buf) {
        bf16x4 v;
        v[0] = (__bf16)a_reg.x; v[1] = (__bf16)a_reg.y;
        v[2] = (__bf16)a_reg.z; v[3] = (__bf16)a_reg.w;
        *(bf16x4*)&Alds[buf][ar * 40 + ac] = v;
    };
    auto asyncB = [&](int k0, int buf) {
#pragma unroll
        for (int i = 0; i < 3; i++)
            glds16(Wt + bsrc_off[i] + k0, &Blds[buf][(i * 256 + w * 64) * 8]);
    };

    loadA(0); asyncB(0, 0); storeA(0);

    for (int k = 0; k < 32; k++) {
        __syncthreads();
        const int kn = k + 1;
        if (kn < 32) { asyncB(kn * 32, kn & 1); loadA(kn * 32); }
        const int buf = k & 1;

        bf16x8 af0 = *(const bf16x8*)&Alds[buf][l15 * 40 + quad * 8];
        bf16x8 af1 = *(const bf16x8*)&Alds[buf][(16 + l15) * 40 + quad * 8];
#pragma unroll
        for (int nt = 0; nt < 3; nt++) {
            const int r  = w * 48 + nt * 16 + l15;
            const int pr = r >> 1;
            const int pc = (quad + ((r & 1) << 2)) ^ (pr & 7);
            bf16x8 bfr = *(const bf16x8*)&Blds[buf][(pr * 8 + pc) * 8];
            acc[nt]     = __builtin_amdgcn_mfma_f32_16x16x32_bf16(af0, bfr, acc[nt], 0, 0, 0);
            acc[3 + nt] = __builtin_amdgcn_mfma_f32_16x16x32_bf16(af1, bfr, acc[3 + nt], 0, 0, 0);
        }
        if (kn < 32) storeA(kn & 1);
    }

    __syncthreads();                        // protect Alds before VtL reuse

    // ---- epilogue: cols 0..63 Q (linear), 64..127 K (chunk-swizzled),
    //      128..191 V -> transpose via VtL (=Alds) then swizzled writeout
    __bf16* VtL = &Alds[0][0];              // [64 h][40], 2560 elems
#pragma unroll
    for (int mt = 0; mt < 2; mt++) {
        const int row0 = m0 + mt * 16 + quad * 4;
#pragma unroll
        for (int nt = 0; nt < 3; nt++) {
            const int col = w * 48 + nt * 16 + l15;
            const f32x4 a = acc[mt * 3 + nt];
            if (col < 64) {
#pragma unroll
                for (int r = 0; r < 4; r++)
                    Qw[(size_t)(row0 + r) * H_ + col] = (__bf16)a[r];
            } else if (col < 128) {
                const int h = col - 64;
#pragma unroll
                for (int r = 0; r < 4; r++) {
                    const int row = row0 + r;
                    const int hs  = (((h >> 3) ^ (row & 7)) << 3) | (h & 7);
                    Kw[(size_t)row * H_ + hs] = (__bf16)a[r];
                }
            } else {
                const int h  = col - 128;
                const int t0 = mt * 16 + quad * 4;
                bf16x4 pv;
                pv[0] = (__bf16)a[0]; pv[1] = (__bf16)a[1];
                pv[2] = (__bf16)a[2]; pv[3] = (__bf16)a[3];
                *(bf16x4*)&VtL[h * 40 + t0] = pv;
            }
        }
    }
    __syncthreads();
    {
        const int bb   = m0 >> 11;
        const int tblk = m0 & 2047;         // multiple of 32
        const int Gb   = tblk & ~63;        // 64-t swizzle group base
        const int g    = (tblk >> 5) & 1;   // which half of the group
        const int h    = tid >> 2;          // 0..63
        const int c    = tid & 3;           // 16B chunk within our 32-t span
        const int p    = ((g << 2) + c) ^ (h & 7);
        *(bf16x8*)(Vtw + (((size_t)(bb * H_ + h)) << 11) + Gb + p * 8) =
            *(const bf16x8*)&VtL[h * 40 + c * 8];
    }
}

// ---------------------------------------------------------------------------
// Kernel 2: paired causal flash attention (UNCHANGED — passed r4, r5).
// ---------------------------------------------------------------------------
#define SCALE_LOG2E 0.18033688011112042f   // (1/sqrt(64)) * log2(e)

__global__ __launch_bounds__(256) void attn_kernel(const __bf16* __restrict__ Qw,
                                                   const __bf16* __restrict__ Kw,
                                                   const __bf16* __restrict__ Vtw,
                                                   float* __restrict__ Opart,
                                                   float* __restrict__ Lpart) {
    __shared__ __align__(16) __bf16 Klds[2][64 * 64];
    __shared__ __align__(16) __bf16 Vlds[2][64 * 64];
    __shared__ __align__(16) __bf16 Plds[2][4][16 * 72];

    const int tid  = threadIdx.x;
    const int w    = tid >> 6;
    const int lane = tid & 63;
    const int quad = lane >> 4;
    const int l15  = lane & 15;

    const int b   = blockIdx.x & 15;
    const int cid = blockIdx.x >> 4;          // 0..39, heavy chunks first
    int i, ci;
    if (cid < 16)      { i = 15 - (cid >> 2); ci = cid & 3; }
    else if (cid < 28) { const int u = cid - 16; i = 11 - u / 3; ci = u % 3; }
    else if (cid < 36) { const int u = cid - 28; i = 7 - (u >> 1); ci = u & 1; }
    else               { i = 3 - (cid - 36); ci = 0; }

    const int jmax = 2 * i + 1;
    const int j0 = ci * 8;
    const int j1 = (j0 + 8 < jmax + 1) ? j0 + 8 : jmax + 1;
    const int nj = j1 - j0;
    const int qA0 = 2 * i * 64;
    const size_t bT = (size_t)b * T_;

    const __bf16* qpA = Qw + (bT + qA0 + w * 16 + l15) * H_ + quad * 8;
    const bf16x8 qfA0 = *(const bf16x8*)qpA;
    const bf16x8 qfA1 = *(const bf16x8*)(qpA + 32);
    const bf16x8 qfB0 = *(const bf16x8*)(qpA + 64 * H_);
    const bf16x8 qfB1 = *(const bf16x8*)(qpA + 64 * H_ + 32);

    float lA = 0.f, lB = 0.f;
    f32x4 accA[4], accB[4];
#pragma unroll
    for (int nt = 0; nt < 4; nt++) {
        accA[nt] = (f32x4){0.f, 0.f, 0.f, 0.f};
        accB[nt] = (f32x4){0.f, 0.f, 0.f, 0.f};
    }

    auto stage = [&](int ts0, int buf) {
        const __bf16* Ks = Kw + (bT + ts0) * H_;
        const __bf16* Vs = Vtw + (((size_t)(b * H_)) << 11) + ts0;
#pragma unroll
        for (int c = 0; c < 2; c++) {
            const int g   = w * 2 + c;
            const int row = g * 8 + (lane >> 3);
            const int cb  = (lane & 7) * 8;
            glds16(Ks + (size_t)row * H_ + cb, &Klds[buf][g * 512]);
            glds16(Vs + ((size_t)row << 11) + cb, &Vlds[buf][g * 512]);
        }
    };

    stage(j0 * 64, 0);

    for (int jj = 0; jj < nj; jj++) {
        const int j = j0 + jj;
        __syncthreads();
        if (jj + 1 < nj) stage((j + 1) * 64, (jj + 1) & 1);
        const int buf = jj & 1;
        const bool doA = (j <= 2 * i);
        const int ts0 = j * 64;
        const int qgA = qA0 + w * 16 + l15;

#pragma unroll
        for (int nt = 0; nt < 4; nt++) {
            const __bf16* kb = &Klds[buf][(nt * 16 + l15) * 64];
            bf16x8 kf0 = *(const bf16x8*)(kb + ((quad ^ (l15 & 7)) << 3));
            bf16x8 kf1 = *(const bf16x8*)(kb + (((4 + quad) ^ (l15 & 7)) << 3));
            const int key0 = ts0 + nt * 16 + quad * 4;

            if (doA) {
                f32x4 z = (f32x4){0.f, 0.f, 0.f, 0.f};
                z = __builtin_amdgcn_mfma_f32_16x16x32_bf16(kf0, qfA0, z, 0, 0, 0);
                z = __builtin_amdgcn_mfma_f32_16x16x32_bf16(kf1, qfA1, z, 0, 0, 0);
                bf16x4 pv;
#pragma unroll
                for (int r = 0; r < 4; r++) {
                    float e = exp2f(__builtin_fmaf(z[r], SCALE_LOG2E, -8.0f));
                    if (j == 2 * i && key0 + r > qgA) e = 0.f;
                    pv[r] = (__bf16)e;
                    lA += e;
                }
                *(bf16x4*)&Plds[0][w][l15 * 72 + nt * 16 + quad * 4] = pv;
            }
            {
                f32x4 z = (f32x4){0.f, 0.f, 0.f, 0.f};
                z = __builtin_amdgcn_mfma_f32_16x16x32_bf16(kf0, qfB0, z, 0, 0, 0);
                z = __builtin_amdgcn_mfma_f32_16x16x32_bf16(kf1, qfB1, z, 0, 0, 0);
                bf16x4 pv;
#pragma unroll
                for (int r = 0; r < 4; r++) {
                    float e = exp2f(__builtin_fmaf(z[r], SCALE_LOG2E, -8.0f));
                    if (j == jmax && key0 + r > qgA + 64) e = 0.f;
                    pv[r] = (__bf16)e;
                    lB += e;
                }
                *(bf16x4*)&Plds[1][w][l15 * 72 + nt * 16 + quad * 4] = pv;
            }
        }
        __asm__ __volatile__("s_waitcnt lgkmcnt(0)" ::: "memory");

        const __bf16* prA = &Plds[0][w][l15 * 72];
        const __bf16* prB = &Plds[1][w][l15 * 72];
        bf16x8 pfA0, pfA1;
        if (doA) {
            pfA0 = *(const bf16x8*)(prA + quad * 8);
            pfA1 = *(const bf16x8*)(prA + 32 + quad * 8);
        }
        bf16x8 pfB0 = *(const bf16x8*)(prB + quad * 8);
        bf16x8 pfB1 = *(const bf16x8*)(prB + 32 + quad * 8);
#pragma unroll
        for (int nt = 0; nt < 4; nt++) {
            const __bf16* vb = &Vlds[buf][(nt * 16 + l15) * 64];
            bf16x8 vf0 = *(const bf16x8*)(vb + ((quad ^ (l15 & 7)) << 3));
            bf16x8 vf1 = *(const bf16x8*)(vb + (((4 + quad) ^ (l15 & 7)) << 3));
            if (doA) {
                accA[nt] = __builtin_amdgcn_mfma_f32_16x16x32_bf16(pfA0, vf0, accA[nt], 0, 0, 0);
                accA[nt] = __builtin_amdgcn_mfma_f32_16x16x32_bf16(pfA1, vf1, accA[nt], 0, 0, 0);
            }
            accB[nt] = __builtin_amdgcn_mfma_f32_16x16x32_bf16(pfB0, vf0, accB[nt], 0, 0, 0);
            accB[nt] = __builtin_amdgcn_mfma_f32_16x16x32_bf16(pfB1, vf1, accB[nt], 0, 0, 0);
        }
    }

    lA += __shfl_xor(lA, 16); lA += __shfl_xor(lA, 32);
    lB += __shfl_xor(lB, 16); lB += __shfl_xor(lB, 32);

    const int qiA = 2 * i;
    const int slotA = ((((b << 5) + qiA) << 2) + ci);
    const int slotB = ((((b << 5) + qiA + 1) << 2) + ci);
    float* OpA = Opart + (size_t)slotA * 4096;
    float* OpB = Opart + (size_t)slotB * 4096;
#pragma unroll
    for (int nt = 0; nt < 4; nt++)
#pragma unroll
        for (int r = 0; r < 4; r++) {
            const int o = (w * 16 + quad * 4 + r) * 64 + nt * 16 + l15;
            OpA[o] = accA[nt][r];
            OpB[o] = accB[nt][r];
        }
    if (quad == 0) {
        Lpart[slotA * 64 + w * 16 + l15] = lA;
        Lpart[slotB * 64 + w * 16 + l15] = lB;
    }
}

// ---------------------------------------------------------------------------
// Kernel 3: combine chunk partials (unchanged).
// ---------------------------------------------------------------------------
__global__ __launch_bounds__(256) void reduce_kernel(const float* __restrict__ Opart,
                                                     const float* __restrict__ Lpart,
                                                     float* __restrict__ out) {
    const int b  = blockIdx.x & 15;
    const int qi = blockIdx.x >> 4;
    const int nc = ((qi & ~1) + 9) >> 3;
    const int tid = threadIdx.x;
    const int q  = tid >> 2;
    const int hc = (tid & 3) * 16;
    const int sbase = ((b << 5) + qi) << 2;

    f32x4 s[4];
#pragma unroll
    for (int i = 0; i < 4; i++) s[i] = (f32x4){0.f, 0.f, 0.f, 0.f};
    float l = 0.f;
    for (int ci = 0; ci < nc; ci++) {
        const float* Op = Opart + (size_t)(sbase + ci) * 4096 + q * 64 + hc;
#pragma unroll
        for (int i = 0; i < 4; i++) s[i] += *(const f32x4*)(Op + i * 4);
        l += Lpart[(sbase + ci) * 64 + q];
    }
    const float inv = 1.f / l;
    float* o = out + ((size_t)b * T_ + qi * 64 + q) * H_ + hc;
#pragma unroll
    for (int i = 0; i < 4; i++) {
        f32x4 r = s[i] * inv;
        *(f32x4*)(o + i * 4) = r;
    }
}

// ---------------------------------------------------------------------------
extern "C" void kernel_launch(void* const* d_in, const int* in_sizes, int n_in,
                              void* d_out, int out_size, void* d_ws, size_t ws_size,
                              hipStream_t stream) {
    const float* x  = (const float*)d_in[0];
    const float* Wq = (const float*)d_in[1];
    const float* Wk = (const float*)d_in[2];
    const float* Wv = (const float*)d_in[3];
    float* out = (float*)d_out;

    __bf16* Qw  = (__bf16*)d_ws;
    __bf16* Kw  = Qw + QK_ELEMS;
    __bf16* Vtw = Kw + QK_ELEMS;
    __bf16* Wt  = Vtw + QK_ELEMS;
    float* Opart = (float*)((char*)d_ws + 16777216);
    float* Lpart = Opart + (size_t)2048 * 4096;

    wt_kernel<<<dim3(48), dim3(256), 0, stream>>>(Wq, Wk, Wv, Wt);
    qkv_kernel<<<dim3((B_ * T_) / 32), dim3(256), 0, stream>>>(x, Wt, Qw, Kw, Vtw);
    attn_kernel<<<dim3(640), dim3(256), 0, stream>>>(Qw, Kw, Vtw, Opart, Lpart);
    reduce_kernel<<<dim3(512), dim3(256), 0, stream>>>(Opart, Lpart, out);
}